// Round 3
// baseline (344.174 us; speedup 1.0000x reference)
//
#include <hip/hip_runtime.h>
#include <hip/hip_bf16.h>
#include <math.h>

#define HIDDEN 1024
#define NH 16
#define HD 64
#define BATCH 2
#define SEQ 2048

typedef __attribute__((ext_vector_type(8))) short bf16x8;
typedef __attribute__((ext_vector_type(4))) float f32x4;

static __device__ __forceinline__ unsigned short f2b(float f) {
    __hip_bfloat16 h = __float2bfloat16(f);
    return __builtin_bit_cast(unsigned short, h);
}

// async global->LDS, 16B per lane. LDS dest must be wave-uniform base + lane*16.
static __device__ __forceinline__ void async16(const unsigned short* g, unsigned short* l) {
    __builtin_amdgcn_global_load_lds(
        (const __attribute__((address_space(1))) unsigned int*)g,
        (__attribute__((address_space(3))) unsigned int*)l, 16, 0, 0);
}

// ---------------------------------------------------------------------------
// Kernel 0: fp32 -> bf16 conversion of X (4M elems) and Wq/Wk/Wv/Wo (1M each)
// into one contiguous 8M-element bf16 region of ws. 4 elems/thread.
// ---------------------------------------------------------------------------
__global__ __launch_bounds__(256)
void cvt_bf16(const float* __restrict__ X,
              const float* __restrict__ Wq, const float* __restrict__ Wk,
              const float* __restrict__ Wv, const float* __restrict__ Wo,
              unsigned short* __restrict__ dst)
{
    const size_t g = (size_t)blockIdx.x * 256 + threadIdx.x;  // group of 4 elems
    const float* src;
    size_t local;
    if (g < 1048576) {            // X: 4M elems = 1M groups
        src = X; local = g;
    } else {
        const size_t gg = g - 1048576;
        const int r = (int)(gg >> 18);        // 262144 groups per weight
        local = gg & 262143;
        src = (r == 0) ? Wq : ((r == 1) ? Wk : ((r == 2) ? Wv : Wo));
    }
    const float4 v = *(const float4*)(src + local * 4);
    ushort4 o;
    o.x = f2b(v.x); o.y = f2b(v.y); o.z = f2b(v.z); o.w = f2b(v.w);
    *(ushort4*)(dst + g * 4) = o;
}

// ---------------------------------------------------------------------------
// Kernel 1: fused QKV projection + bias + RoPE.
// grid (32, 24): y>>3 selects proj (0=q,1=k,2=v), y&7 is the 128-col N tile.
// Writes q/k/v as bf16 in (B, NH, S, D) layout. Biases read as fp32.
// ---------------------------------------------------------------------------
__global__ __launch_bounds__(256, 2)
void qkv_rope(const unsigned short* __restrict__ X,
              const unsigned short* __restrict__ Wqb, const float* __restrict__ bq,
              const unsigned short* __restrict__ Wkb, const float* __restrict__ bk,
              const unsigned short* __restrict__ Wvb, const float* __restrict__ bv,
              unsigned short* __restrict__ qw, unsigned short* __restrict__ kw,
              unsigned short* __restrict__ vw)
{
    const int proj = blockIdx.y >> 3;
    const unsigned short* W = (proj == 0) ? Wqb : ((proj == 1) ? Wkb : Wvb);
    const float* bias       = (proj == 0) ? bq : ((proj == 1) ? bk : bv);
    unsigned short* outp    = (proj == 0) ? qw : ((proj == 1) ? kw : vw);
    const int tn = (blockIdx.y & 7) * 128;
    const int tm = blockIdx.x * 128;

    __shared__ __align__(16) unsigned short As[128 * 32];
    __shared__ __align__(16) unsigned short Bs[128 * 32];

    const int tid  = threadIdx.x;
    const int lane = tid & 63;
    const int wave = tid >> 6;
    const int quad = lane >> 4;
    const int l16  = lane & 15;
    const int wm   = (wave & 1) * 64;
    const int wn   = (wave >> 1) * 64;

    const int r0 = tid >> 2;
    const int c0 = (tid & 3) * 8;
    const unsigned short* Ag = X + (size_t)(tm + r0) * HIDDEN + c0;
    const unsigned short* Bg = W + (size_t)(tn + r0) * HIDDEN + c0;
    unsigned short* lA = As + tid * 8;
    unsigned short* lB = Bs + tid * 8;

    f32x4 acc[4][4] = {};

    for (int k0 = 0; k0 < HIDDEN; k0 += 32) {
        __syncthreads();
        async16(Ag + k0, lA);
        async16(Ag + 64 * HIDDEN + k0, lA + 2048);
        async16(Bg + k0, lB);
        async16(Bg + 64 * HIDDEN + k0, lB + 2048);
        __syncthreads();
        bf16x8 af[4], bfr[4];
#pragma unroll
        for (int i = 0; i < 4; ++i)
            af[i] = *(const bf16x8*)(As + (wm + i * 16 + l16) * 32 + quad * 8);
#pragma unroll
        for (int j = 0; j < 4; ++j)
            bfr[j] = *(const bf16x8*)(Bs + (wn + j * 16 + l16) * 32 + quad * 8);
#pragma unroll
        for (int i = 0; i < 4; ++i)
#pragma unroll
            for (int j = 0; j < 4; ++j)
                acc[i][j] = __builtin_amdgcn_mfma_f32_16x16x32_bf16(af[i], bfr[j], acc[i][j], 0, 0, 0);
    }

    // Epilogue: bias + RoPE + store to (B,NH,S,D).
    // Within a wave the 64 cols are exactly one head; partner d^32 = frag j^2.
    const bool dorope = (proj < 2);
    float bsv[4];
#pragma unroll
    for (int j = 0; j < 4; ++j) bsv[j] = bias[tn + wn + j * 16 + l16];
    float inv_e = 0.f, inv_o = 0.f;
    if (dorope) {
        // 10000^(-f/32) = 2^(-f*log2(10000)/32); log2(10000)/32 = 0.41524101186...
        const float LB = 0.4152410118609203f;
        inv_e = exp2f(-LB * (float)l16);          // freq idx = l16      (j even)
        inv_o = exp2f(-LB * (float)(16 + l16));   // freq idx = 16+l16   (j odd)
    }
#pragma unroll
    for (int i = 0; i < 4; ++i) {
#pragma unroll
        for (int r = 0; r < 4; ++r) {
            const int m = tm + wm + i * 16 + quad * 4 + r;  // C/D row = quad*4+r
            const int b = m >> 11;
            const int s = m & (SEQ - 1);
            float cs0 = 1.f, sn0 = 0.f, cs1 = 1.f, sn1 = 0.f;
            if (dorope) {
                const float sf = (float)s;
                __sincosf(sf * inv_e, &sn0, &cs0);
                __sincosf(sf * inv_o, &sn1, &cs1);
            }
#pragma unroll
            for (int j = 0; j < 4; ++j) {
                const int n = tn + wn + j * 16 + l16;       // C/D col = lane&15
                const float v = acc[i][j][r] + bsv[j];
                float o = v;
                if (dorope) {
                    const float vp = acc[i][j ^ 2][r] + bsv[j ^ 2];
                    o = v * ((j & 1) ? cs1 : cs0) + ((j < 2) ? -vp : vp) * ((j & 1) ? sn1 : sn0);
                }
                const int h = n >> 6;
                const int d = n & 63;
                outp[(((size_t)(b * NH + h)) * SEQ + s) * HD + d] = f2b(o);
            }
        }
    }
}

// ---------------------------------------------------------------------------
// Kernel 2: flash attention. grid (16 q-tiles, 32 b*h), block 256 (4 waves).
// LDS kept at 52224 B (single Vt buffer -> 2 blocks/CU resident; the 68KB
// dbuf version dropped residency to 1 block/CU and regressed 131->211us).
// Keeps: XCD remap (K/V L2-resident, FETCH 69.7->12.4MB), XOR-swizzled Vt
// (conflicts 1.78e7->3.1e6), log2 softmax + defer-max, early V-load hoist.
// Barrier order: QK^T -> softmax -> bar1 -> Vt scatter -> bar2 -> PV, so the
// inter-barrier serialized span is only the scatter.
// ---------------------------------------------------------------------------
__global__ __launch_bounds__(256, 1)
void attn_fwd(const unsigned short* __restrict__ qb, const unsigned short* __restrict__ kb,
              const unsigned short* __restrict__ vb, unsigned short* __restrict__ ob)
{
    // XCD-aware remap: 512 blocks = 8 XCDs * 64. Each XCD gets 4 consecutive
    // (b,h) pairs (all 16 q-tiles of a head on one XCD -> K/V L2-resident).
    const int flat  = blockIdx.y * gridDim.x + blockIdx.x;  // dispatch-linear
    const int flat2 = (flat & 7) * 64 + (flat >> 3);        // bijective, 512=8*64
    const int bh = flat2 >> 4;
    const int qt = flat2 & 15;
    const int b  = bh >> 4;
    const int h  = bh & 15;
    const unsigned short* Q = qb + (size_t)bh * SEQ * HD;
    const unsigned short* K = kb + (size_t)bh * SEQ * HD;
    const unsigned short* V = vb + (size_t)bh * SEQ * HD;

    const int tid  = threadIdx.x;
    const int wave = tid >> 6;
    const int lane = tid & 63;
    const int quad = lane >> 4;
    const int l16  = lane & 15;
    const int q0   = qt * 128 + wave * 32;

    __shared__ __align__(16) unsigned short Pb[4][32 * 136];  // per-wave P, stride 136
    __shared__ __align__(16) unsigned short Vt[64 * 136];     // V^T, swizzled cols

    // Q fragments (A operand): held in registers for all K tiles
    bf16x8 qf[2][2];
#pragma unroll
    for (int mt = 0; mt < 2; ++mt)
#pragma unroll
        for (int kk = 0; kk < 2; ++kk)
            qf[mt][kk] = *(const bf16x8*)(Q + (size_t)(q0 + mt * 16 + l16) * HD + kk * 32 + quad * 8);

    f32x4 oacc[2][4] = {};
    float mr[2][4], lr[2][4];
#pragma unroll
    for (int mt = 0; mt < 2; ++mt)
#pragma unroll
        for (int r = 0; r < 4; ++r) { mr[mt][r] = -3.0e38f; lr[mt][r] = 0.f; }

    // V staging geometry: thread loads V[t0+vkey+32p][vd0..vd0+7], scatters
    // transposed with column swizzle ky ^ (vm<<3) (vm = (d>>3)&7, constant).
    const int vkey = tid >> 3;          // 0..31
    const int vd0  = (tid & 7) * 8;
    const int vm   = tid & 7;

    const float KSCL = 0.18033688011112042f;  // 0.125 * log2(e)

    for (int kt = 0; kt < SEQ / 128; ++kt) {
        const int t0 = kt * 128;

        // issue V loads early; latency hides under QK^T MFMAs
        bf16x8 vv[4];
#pragma unroll
        for (int p = 0; p < 4; ++p)
            vv[p] = *(const bf16x8*)(V + (size_t)(t0 + vkey + 32 * p) * HD + vd0);

        // S = Q K^T for this tile
        f32x4 sc[2][8] = {};
#pragma unroll
        for (int kk = 0; kk < 2; ++kk) {
            bf16x8 kf[8];
#pragma unroll
            for (int jj = 0; jj < 8; ++jj)
                kf[jj] = *(const bf16x8*)(K + (size_t)(t0 + jj * 16 + l16) * HD + kk * 32 + quad * 8);
#pragma unroll
            for (int mt = 0; mt < 2; ++mt)
#pragma unroll
                for (int jj = 0; jj < 8; ++jj)
                    sc[mt][jj] = __builtin_amdgcn_mfma_f32_16x16x32_bf16(qf[mt][kk], kf[jj], sc[mt][jj], 0, 0, 0);
        }

        // online softmax in log2 domain (row stats live in the quad's 16 lanes)
        // Pb is wave-local: no barrier needed around its write/read.
#pragma unroll
        for (int mt = 0; mt < 2; ++mt) {
#pragma unroll
            for (int r = 0; r < 4; ++r) {
                float mx = sc[mt][0][r];
#pragma unroll
                for (int jj = 1; jj < 8; ++jj) mx = fmaxf(mx, sc[mt][jj][r]);
                float ms = mx * KSCL;
#pragma unroll
                for (int off = 8; off; off >>= 1) ms = fmaxf(ms, __shfl_xor(ms, off));
                const float mold = mr[mt][r];
                const bool stable = __all(ms <= mold + 8.0f) != 0;  // T13 defer-max
                const float mnew = stable ? mold : fmaxf(mold, ms);
                float pe[8];
                float ps = 0.f;
#pragma unroll
                for (int jj = 0; jj < 8; ++jj) {
                    pe[jj] = exp2f(sc[mt][jj][r] * KSCL - mnew);
                    ps += pe[jj];
                }
                const int prow = (mt * 16 + quad * 4 + r) * 136;
#pragma unroll
                for (int jj = 0; jj < 8; ++jj)
                    Pb[wave][prow + jj * 16 + l16] = f2b(pe[jj]);
#pragma unroll
                for (int off = 8; off; off >>= 1) ps += __shfl_xor(ps, off);
                if (stable) {
                    lr[mt][r] += ps;
                } else {
                    const float alpha = exp2f(mold - mnew);
                    mr[mt][r] = mnew;
                    lr[mt][r] = lr[mt][r] * alpha + ps;
#pragma unroll
                    for (int nn = 0; nn < 4; ++nn) oacc[mt][nn][r] *= alpha;
                }
            }
        }

        __syncthreads();  // previous tile's Vt reads complete before overwrite

        // V^T scatter, swizzled: write V[ky][d] at Vt[d*136 + (ky ^ (vm<<3))]
        // -> the 8 lanes sharing ky land on 8 distinct banks (was 8-way).
#pragma unroll
        for (int p = 0; p < 4; ++p) {
            const int cs = (vkey + 32 * p) ^ (vm << 3);
#pragma unroll
            for (int u = 0; u < 8; ++u)
                Vt[(vd0 + u) * 136 + cs] = ((const unsigned short*)&vv[p])[u];
        }

        __syncthreads();  // Vt writes visible

        // O += P V   (A = P from LDS, B = swizzled V^T from LDS)
#pragma unroll
        for (int kk2 = 0; kk2 < 4; ++kk2) {
            bf16x8 pf[2], vf[4];
#pragma unroll
            for (int mt = 0; mt < 2; ++mt)
                pf[mt] = *(const bf16x8*)(&Pb[wave][(mt * 16 + l16) * 136 + kk2 * 32 + quad * 8]);
#pragma unroll
            for (int nn = 0; nn < 4; ++nn) {
                const int d   = nn * 16 + l16;
                const int mrd = (nn * 2 + (l16 >> 3)) & 7;               // (d>>3)&7
                const int cb  = (kk2 * 32 + quad * 8) ^ (mrd << 3);      // swizzled col base
                vf[nn] = *(const bf16x8*)(&Vt[d * 136 + cb]);
            }
#pragma unroll
            for (int mt = 0; mt < 2; ++mt)
#pragma unroll
                for (int nn = 0; nn < 4; ++nn)
                    oacc[mt][nn] = __builtin_amdgcn_mfma_f32_16x16x32_bf16(pf[mt], vf[nn], oacc[mt][nn], 0, 0, 0);
        }
    }

    // normalize + store to (B,S,H)
#pragma unroll
    for (int mt = 0; mt < 2; ++mt) {
#pragma unroll
        for (int r = 0; r < 4; ++r) {
            const float inv = 1.0f / lr[mt][r];
            const int s = q0 + mt * 16 + quad * 4 + r;
#pragma unroll
            for (int nn = 0; nn < 4; ++nn) {
                const int d = nn * 16 + l16;
                ob[((size_t)(b * SEQ + s)) * HIDDEN + h * HD + d] = f2b(oacc[mt][nn][r] * inv);
            }
        }
    }
}

// ---------------------------------------------------------------------------
// Kernel 3: output projection GEMM + fp32 bias. grid (32, 8). Output FP32.
// ---------------------------------------------------------------------------
__global__ __launch_bounds__(256, 2)
void out_proj(const unsigned short* __restrict__ A,
              const unsigned short* __restrict__ W,
              const float* __restrict__ bias,
              float* __restrict__ out)
{
    const int tn = blockIdx.y * 128;
    const int tm = blockIdx.x * 128;

    __shared__ __align__(16) unsigned short As[128 * 32];
    __shared__ __align__(16) unsigned short Bs[128 * 32];

    const int tid  = threadIdx.x;
    const int lane = tid & 63;
    const int wave = tid >> 6;
    const int quad = lane >> 4;
    const int l16  = lane & 15;
    const int wm   = (wave & 1) * 64;
    const int wn   = (wave >> 1) * 64;

    const int r0 = tid >> 2;
    const int c0 = (tid & 3) * 8;
    const unsigned short* Ag = A + (size_t)(tm + r0) * HIDDEN + c0;
    const unsigned short* Bg = W + (size_t)(tn + r0) * HIDDEN + c0;
    unsigned short* lA = As + tid * 8;
    unsigned short* lB = Bs + tid * 8;

    f32x4 acc[4][4] = {};

    for (int k0 = 0; k0 < HIDDEN; k0 += 32) {
        __syncthreads();
        async16(Ag + k0, lA);
        async16(Ag + 64 * HIDDEN + k0, lA + 2048);
        async16(Bg + k0, lB);
        async16(Bg + 64 * HIDDEN + k0, lB + 2048);
        __syncthreads();
        bf16x8 af[4], bfr[4];
#pragma unroll
        for (int i = 0; i < 4; ++i)
            af[i] = *(const bf16x8*)(As + (wm + i * 16 + l16) * 32 + quad * 8);
#pragma unroll
        for (int j = 0; j < 4; ++j)
            bfr[j] = *(const bf16x8*)(Bs + (wn + j * 16 + l16) * 32 + quad * 8);
#pragma unroll
        for (int i = 0; i < 4; ++i)
#pragma unroll
            for (int j = 0; j < 4; ++j)
                acc[i][j] = __builtin_amdgcn_mfma_f32_16x16x32_bf16(af[i], bfr[j], acc[i][j], 0, 0, 0);
    }

    float bsv[4];
#pragma unroll
    for (int j = 0; j < 4; ++j) bsv[j] = bias[tn + wn + j * 16 + l16];
#pragma unroll
    for (int i = 0; i < 4; ++i) {
#pragma unroll
        for (int r = 0; r < 4; ++r) {
            const int m = tm + wm + i * 16 + quad * 4 + r;
#pragma unroll
            for (int j = 0; j < 4; ++j) {
                const int n = tn + wn + j * 16 + l16;
                out[(size_t)m * HIDDEN + n] = acc[i][j][r] + bsv[j];   // fp32 output
            }
        }
    }
}

extern "C" void kernel_launch(void* const* d_in, const int* in_sizes, int n_in,
                              void* d_out, int out_size, void* d_ws, size_t ws_size,
                              hipStream_t stream) {
    // Inputs fp32 (setup_inputs uses dtype=jnp.float32); output fp32.
    const float* hs = (const float*)d_in[0];
    const float* Wq = (const float*)d_in[1];
    const float* bq = (const float*)d_in[2];
    const float* Wk = (const float*)d_in[3];
    const float* bk = (const float*)d_in[4];
    const float* Wv = (const float*)d_in[5];
    const float* bv = (const float*)d_in[6];
    const float* Wo = (const float*)d_in[7];
    const float* bo = (const float*)d_in[8];
    float* out = (float*)d_out;

    // ws layout (bf16 elements): Xb[4M] Wqb[1M] Wkb[1M] Wvb[1M] Wob[1M]
    //                            qw[4M] kw[4M] vw[4M] aw[4M]  = 48 MB total
    unsigned short* Xb  = (unsigned short*)d_ws;
    unsigned short* Wqb = Xb + 4194304;
    unsigned short* Wkb = Wqb + 1048576;
    unsigned short* Wvb = Wkb + 1048576;
    unsigned short* Wob = Wvb + 1048576;
    unsigned short* qw  = Wob + 1048576;
    unsigned short* kw  = qw + 4194304;
    unsigned short* vw  = kw + 4194304;
    unsigned short* aw  = vw + 4194304;

    cvt_bf16<<<dim3(8192), 256, 0, stream>>>(hs, Wq, Wk, Wv, Wo, Xb);
    qkv_rope<<<dim3(32, 24), 256, 0, stream>>>(Xb, Wqb, bq, Wkb, bk, Wvb, bv, qw, kw, vw);
    attn_fwd<<<dim3(16, 32), 256, 0, stream>>>(qw, kw, vw, aw);
    out_proj<<<dim3(32, 8), 256, 0, stream>>>(aw, Wob, bo, out);
}

// Round 4
// 255.712 us; speedup vs baseline: 1.3459x; 1.3459x over previous
//
#include <hip/hip_runtime.h>
#include <hip/hip_bf16.h>
#include <math.h>

#define HIDDEN 1024
#define NH 16
#define HD 64
#define BATCH 2
#define SEQ 2048

typedef __attribute__((ext_vector_type(8))) short bf16x8;
typedef __attribute__((ext_vector_type(4))) float f32x4;

static __device__ __forceinline__ unsigned short f2b(float f) {
    __hip_bfloat16 h = __float2bfloat16(f);
    return __builtin_bit_cast(unsigned short, h);
}

static __device__ __forceinline__ float fexp2(float x) {
    return __builtin_amdgcn_exp2f(x);   // v_exp_f32, single instruction
}

// async global->LDS, 16B per lane. LDS dest must be wave-uniform base + lane*16.
static __device__ __forceinline__ void async16(const unsigned short* g, unsigned short* l) {
    __builtin_amdgcn_global_load_lds(
        (const __attribute__((address_space(1))) unsigned int*)g,
        (__attribute__((address_space(3))) unsigned int*)l, 16, 0, 0);
}

// ---------------------------------------------------------------------------
// Kernel 0: fp32 -> bf16 conversion of X (4M elems) and Wq/Wk/Wv/Wo (1M each)
// into one contiguous 8M-element bf16 region of ws. 4 elems/thread.
// ---------------------------------------------------------------------------
__global__ __launch_bounds__(256)
void cvt_bf16(const float* __restrict__ X,
              const float* __restrict__ Wq, const float* __restrict__ Wk,
              const float* __restrict__ Wv, const float* __restrict__ Wo,
              unsigned short* __restrict__ dst)
{
    const size_t g = (size_t)blockIdx.x * 256 + threadIdx.x;  // group of 4 elems
    const float* src;
    size_t local;
    if (g < 1048576) {            // X: 4M elems = 1M groups
        src = X; local = g;
    } else {
        const size_t gg = g - 1048576;
        const int r = (int)(gg >> 18);        // 262144 groups per weight
        local = gg & 262143;
        src = (r == 0) ? Wq : ((r == 1) ? Wk : ((r == 2) ? Wv : Wo));
    }
    const float4 v = *(const float4*)(src + local * 4);
    ushort4 o;
    o.x = f2b(v.x); o.y = f2b(v.y); o.z = f2b(v.z); o.w = f2b(v.w);
    *(ushort4*)(dst + g * 4) = o;
}

// ---------------------------------------------------------------------------
// Kernel 1: fused QKV projection + bias + RoPE.
// grid (32, 24): y>>3 selects proj (0=q,1=k,2=v), y&7 is the 128-col N tile.
// Writes q/k/v as bf16 in (B, NH, S, D) layout. Biases read as fp32.
// ---------------------------------------------------------------------------
__global__ __launch_bounds__(256, 2)
void qkv_rope(const unsigned short* __restrict__ X,
              const unsigned short* __restrict__ Wqb, const float* __restrict__ bq,
              const unsigned short* __restrict__ Wkb, const float* __restrict__ bk,
              const unsigned short* __restrict__ Wvb, const float* __restrict__ bv,
              unsigned short* __restrict__ qw, unsigned short* __restrict__ kw,
              unsigned short* __restrict__ vw)
{
    const int proj = blockIdx.y >> 3;
    const unsigned short* W = (proj == 0) ? Wqb : ((proj == 1) ? Wkb : Wvb);
    const float* bias       = (proj == 0) ? bq : ((proj == 1) ? bk : bv);
    unsigned short* outp    = (proj == 0) ? qw : ((proj == 1) ? kw : vw);
    const int tn = (blockIdx.y & 7) * 128;
    const int tm = blockIdx.x * 128;

    __shared__ __align__(16) unsigned short As[128 * 32];
    __shared__ __align__(16) unsigned short Bs[128 * 32];

    const int tid  = threadIdx.x;
    const int lane = tid & 63;
    const int wave = tid >> 6;
    const int quad = lane >> 4;
    const int l16  = lane & 15;
    const int wm   = (wave & 1) * 64;
    const int wn   = (wave >> 1) * 64;

    const int r0 = tid >> 2;
    const int c0 = (tid & 3) * 8;
    const unsigned short* Ag = X + (size_t)(tm + r0) * HIDDEN + c0;
    const unsigned short* Bg = W + (size_t)(tn + r0) * HIDDEN + c0;
    unsigned short* lA = As + tid * 8;
    unsigned short* lB = Bs + tid * 8;

    f32x4 acc[4][4] = {};

    for (int k0 = 0; k0 < HIDDEN; k0 += 32) {
        __syncthreads();
        async16(Ag + k0, lA);
        async16(Ag + 64 * HIDDEN + k0, lA + 2048);
        async16(Bg + k0, lB);
        async16(Bg + 64 * HIDDEN + k0, lB + 2048);
        __syncthreads();
        bf16x8 af[4], bfr[4];
#pragma unroll
        for (int i = 0; i < 4; ++i)
            af[i] = *(const bf16x8*)(As + (wm + i * 16 + l16) * 32 + quad * 8);
#pragma unroll
        for (int j = 0; j < 4; ++j)
            bfr[j] = *(const bf16x8*)(Bs + (wn + j * 16 + l16) * 32 + quad * 8);
#pragma unroll
        for (int i = 0; i < 4; ++i)
#pragma unroll
            for (int j = 0; j < 4; ++j)
                acc[i][j] = __builtin_amdgcn_mfma_f32_16x16x32_bf16(af[i], bfr[j], acc[i][j], 0, 0, 0);
    }

    // Epilogue: bias + RoPE + store to (B,NH,S,D).
    // Within a wave the 64 cols are exactly one head; partner d^32 = frag j^2.
    const bool dorope = (proj < 2);
    float bsv[4];
#pragma unroll
    for (int j = 0; j < 4; ++j) bsv[j] = bias[tn + wn + j * 16 + l16];
    float inv_e = 0.f, inv_o = 0.f;
    if (dorope) {
        // 10000^(-f/32) = 2^(-f*log2(10000)/32); log2(10000)/32 = 0.41524101186...
        const float LB = 0.4152410118609203f;
        inv_e = exp2f(-LB * (float)l16);          // freq idx = l16      (j even)
        inv_o = exp2f(-LB * (float)(16 + l16));   // freq idx = 16+l16   (j odd)
    }
#pragma unroll
    for (int i = 0; i < 4; ++i) {
#pragma unroll
        for (int r = 0; r < 4; ++r) {
            const int m = tm + wm + i * 16 + quad * 4 + r;  // C/D row = quad*4+r
            const int b = m >> 11;
            const int s = m & (SEQ - 1);
            float cs0 = 1.f, sn0 = 0.f, cs1 = 1.f, sn1 = 0.f;
            if (dorope) {
                const float sf = (float)s;
                __sincosf(sf * inv_e, &sn0, &cs0);
                __sincosf(sf * inv_o, &sn1, &cs1);
            }
#pragma unroll
            for (int j = 0; j < 4; ++j) {
                const int n = tn + wn + j * 16 + l16;       // C/D col = lane&15
                const float v = acc[i][j][r] + bsv[j];
                float o = v;
                if (dorope) {
                    const float vp = acc[i][j ^ 2][r] + bsv[j ^ 2];
                    o = v * ((j & 1) ? cs1 : cs0) + ((j < 2) ? -vp : vp) * ((j & 1) ? sn1 : sn0);
                }
                const int h = n >> 6;
                const int d = n & 63;
                outp[(((size_t)(b * NH + h)) * SEQ + s) * HD + d] = f2b(o);
            }
        }
    }
}

// ---------------------------------------------------------------------------
// Kernel 2: flash attention. grid (16 q-tiles, 32 b*h), block 256 (4 waves).
// Residency is the lever: baseline (124 VGPR) ran 2 blocks/CU (occ 20%);
// rounds 2-3 (136-156 VGPR) fell off the unified-file cliff (arch+acc > 256
// per wave) to 1 block/CU (occ 11.7%) and ran 1.6x slower despite winning on
// conflicts and FETCH. This round: baseline register structure restored
// (V loads in scatter phase, no pe[] staging array) + __launch_bounds__(256,2)
// to ENFORCE 2 waves/SIMD. Kept register-neutral wins: XCD remap, Vt XOR
// swizzle, log2-domain softmax (v_exp_f32), defer-max.
// ---------------------------------------------------------------------------
__global__ __launch_bounds__(256, 2)
void attn_fwd(const unsigned short* __restrict__ qb, const unsigned short* __restrict__ kb,
              const unsigned short* __restrict__ vb, unsigned short* __restrict__ ob)
{
    // XCD-aware remap: 512 blocks = 8 XCDs * 64. Each XCD gets 4 consecutive
    // (b,h) pairs (all 16 q-tiles of a head on one XCD -> K/V L2-resident).
    const int flat  = blockIdx.y * gridDim.x + blockIdx.x;  // dispatch-linear
    const int flat2 = (flat & 7) * 64 + (flat >> 3);        // bijective, 512=8*64
    const int bh = flat2 >> 4;
    const int qt = flat2 & 15;
    const int b  = bh >> 4;
    const int h  = bh & 15;
    const unsigned short* Q = qb + (size_t)bh * SEQ * HD;
    const unsigned short* K = kb + (size_t)bh * SEQ * HD;
    const unsigned short* V = vb + (size_t)bh * SEQ * HD;

    const int tid  = threadIdx.x;
    const int wave = tid >> 6;
    const int lane = tid & 63;
    const int quad = lane >> 4;
    const int l16  = lane & 15;
    const int q0   = qt * 128 + wave * 32;

    __shared__ __align__(16) unsigned short Pb[4][32 * 136];  // per-wave P, stride 136
    __shared__ __align__(16) unsigned short Vt[64 * 136];     // V^T, swizzled cols

    // Q fragments (A operand): held in registers for all K tiles
    bf16x8 qf[2][2];
#pragma unroll
    for (int mt = 0; mt < 2; ++mt)
#pragma unroll
        for (int kk = 0; kk < 2; ++kk)
            qf[mt][kk] = *(const bf16x8*)(Q + (size_t)(q0 + mt * 16 + l16) * HD + kk * 32 + quad * 8);

    f32x4 oacc[2][4] = {};
    float mr[2][4], lr[2][4];
#pragma unroll
    for (int mt = 0; mt < 2; ++mt)
#pragma unroll
        for (int r = 0; r < 4; ++r) { mr[mt][r] = -3.0e38f; lr[mt][r] = 0.f; }

    // V staging geometry: thread loads V[t0+vkey+32p][vd0..vd0+7], scatters
    // transposed with column swizzle ky ^ (vm<<3) (vm = (d>>3)&7, constant).
    const int vkey = tid >> 3;          // 0..31
    const int vd0  = (tid & 7) * 8;
    const int vm   = tid & 7;

    const float KSCL = 0.18033688011112042f;  // 0.125 * log2(e)

    for (int kt = 0; kt < SEQ / 128; ++kt) {
        const int t0 = kt * 128;

        // S = Q K^T for this tile
        f32x4 sc[2][8] = {};
#pragma unroll
        for (int kk = 0; kk < 2; ++kk) {
            bf16x8 kf[8];
#pragma unroll
            for (int jj = 0; jj < 8; ++jj)
                kf[jj] = *(const bf16x8*)(K + (size_t)(t0 + jj * 16 + l16) * HD + kk * 32 + quad * 8);
#pragma unroll
            for (int mt = 0; mt < 2; ++mt)
#pragma unroll
                for (int jj = 0; jj < 8; ++jj)
                    sc[mt][jj] = __builtin_amdgcn_mfma_f32_16x16x32_bf16(qf[mt][kk], kf[jj], sc[mt][jj], 0, 0, 0);
        }

        __syncthreads();  // previous tile's Vt reads complete before overwrite

        // V load + V^T scatter, swizzled: V[ky][d] -> Vt[d*136 + (ky^(vm<<3))]
        // -> the 8 lanes sharing ky land on 8 distinct banks (was 8-way).
#pragma unroll
        for (int p = 0; p < 4; ++p) {
            const int ky = vkey + 32 * p;
            const int cs = ky ^ (vm << 3);
            bf16x8 vv = *(const bf16x8*)(V + (size_t)(t0 + ky) * HD + vd0);
#pragma unroll
            for (int u = 0; u < 8; ++u)
                Vt[(vd0 + u) * 136 + cs] = ((const unsigned short*)&vv)[u];
        }

        // online softmax in log2 domain (row stats live in the quad's 16 lanes)
#pragma unroll
        for (int mt = 0; mt < 2; ++mt) {
#pragma unroll
            for (int r = 0; r < 4; ++r) {
                float mx = sc[mt][0][r];
#pragma unroll
                for (int jj = 1; jj < 8; ++jj) mx = fmaxf(mx, sc[mt][jj][r]);
                float ms = mx * KSCL;
#pragma unroll
                for (int off = 8; off; off >>= 1) ms = fmaxf(ms, __shfl_xor(ms, off));
                const float mold = mr[mt][r];
                const bool stable = __all(ms <= mold + 8.0f) != 0;  // T13 defer-max
                const float mnew = stable ? mold : fmaxf(mold, ms);
                float ps = 0.f;
                const int prow = (mt * 16 + quad * 4 + r) * 136;
#pragma unroll
                for (int jj = 0; jj < 8; ++jj) {
                    const float p = fexp2(sc[mt][jj][r] * KSCL - mnew);
                    ps += p;
                    Pb[wave][prow + jj * 16 + l16] = f2b(p);
                }
#pragma unroll
                for (int off = 8; off; off >>= 1) ps += __shfl_xor(ps, off);
                if (stable) {
                    lr[mt][r] += ps;
                } else {
                    const float alpha = fexp2(mold - mnew);
                    mr[mt][r] = mnew;
                    lr[mt][r] = lr[mt][r] * alpha + ps;
#pragma unroll
                    for (int nn = 0; nn < 4; ++nn) oacc[mt][nn][r] *= alpha;
                }
            }
        }

        __syncthreads();  // Vt writes visible

        // O += P V   (A = P from LDS, B = swizzled V^T from LDS)
#pragma unroll
        for (int kk2 = 0; kk2 < 4; ++kk2) {
            bf16x8 pf[2], vf[4];
#pragma unroll
            for (int mt = 0; mt < 2; ++mt)
                pf[mt] = *(const bf16x8*)(&Pb[wave][(mt * 16 + l16) * 136 + kk2 * 32 + quad * 8]);
#pragma unroll
            for (int nn = 0; nn < 4; ++nn) {
                const int d   = nn * 16 + l16;
                const int mrd = (nn * 2 + (l16 >> 3)) & 7;               // (d>>3)&7
                const int cb  = (kk2 * 32 + quad * 8) ^ (mrd << 3);      // swizzled col base
                vf[nn] = *(const bf16x8*)(&Vt[d * 136 + cb]);
            }
#pragma unroll
            for (int mt = 0; mt < 2; ++mt)
#pragma unroll
                for (int nn = 0; nn < 4; ++nn)
                    oacc[mt][nn] = __builtin_amdgcn_mfma_f32_16x16x32_bf16(pf[mt], vf[nn], oacc[mt][nn], 0, 0, 0);
        }
    }

    // normalize + store to (B,S,H)
#pragma unroll
    for (int mt = 0; mt < 2; ++mt) {
#pragma unroll
        for (int r = 0; r < 4; ++r) {
            const float inv = 1.0f / lr[mt][r];
            const int s = q0 + mt * 16 + quad * 4 + r;
#pragma unroll
            for (int nn = 0; nn < 4; ++nn) {
                const int d = nn * 16 + l16;
                ob[((size_t)(b * SEQ + s)) * HIDDEN + h * HD + d] = f2b(oacc[mt][nn][r] * inv);
            }
        }
    }
}

// ---------------------------------------------------------------------------
// Kernel 3: output projection GEMM + fp32 bias. grid (32, 8). Output FP32.
// ---------------------------------------------------------------------------
__global__ __launch_bounds__(256, 2)
void out_proj(const unsigned short* __restrict__ A,
              const unsigned short* __restrict__ W,
              const float* __restrict__ bias,
              float* __restrict__ out)
{
    const int tn = blockIdx.y * 128;
    const int tm = blockIdx.x * 128;

    __shared__ __align__(16) unsigned short As[128 * 32];
    __shared__ __align__(16) unsigned short Bs[128 * 32];

    const int tid  = threadIdx.x;
    const int lane = tid & 63;
    const int wave = tid >> 6;
    const int quad = lane >> 4;
    const int l16  = lane & 15;
    const int wm   = (wave & 1) * 64;
    const int wn   = (wave >> 1) * 64;

    const int r0 = tid >> 2;
    const int c0 = (tid & 3) * 8;
    const unsigned short* Ag = A + (size_t)(tm + r0) * HIDDEN + c0;
    const unsigned short* Bg = W + (size_t)(tn + r0) * HIDDEN + c0;
    unsigned short* lA = As + tid * 8;
    unsigned short* lB = Bs + tid * 8;

    f32x4 acc[4][4] = {};

    for (int k0 = 0; k0 < HIDDEN; k0 += 32) {
        __syncthreads();
        async16(Ag + k0, lA);
        async16(Ag + 64 * HIDDEN + k0, lA + 2048);
        async16(Bg + k0, lB);
        async16(Bg + 64 * HIDDEN + k0, lB + 2048);
        __syncthreads();
        bf16x8 af[4], bfr[4];
#pragma unroll
        for (int i = 0; i < 4; ++i)
            af[i] = *(const bf16x8*)(As + (wm + i * 16 + l16) * 32 + quad * 8);
#pragma unroll
        for (int j = 0; j < 4; ++j)
            bfr[j] = *(const bf16x8*)(Bs + (wn + j * 16 + l16) * 32 + quad * 8);
#pragma unroll
        for (int i = 0; i < 4; ++i)
#pragma unroll
            for (int j = 0; j < 4; ++j)
                acc[i][j] = __builtin_amdgcn_mfma_f32_16x16x32_bf16(af[i], bfr[j], acc[i][j], 0, 0, 0);
    }

    float bsv[4];
#pragma unroll
    for (int j = 0; j < 4; ++j) bsv[j] = bias[tn + wn + j * 16 + l16];
#pragma unroll
    for (int i = 0; i < 4; ++i) {
#pragma unroll
        for (int r = 0; r < 4; ++r) {
            const int m = tm + wm + i * 16 + quad * 4 + r;
#pragma unroll
            for (int j = 0; j < 4; ++j) {
                const int n = tn + wn + j * 16 + l16;
                out[(size_t)m * HIDDEN + n] = acc[i][j][r] + bsv[j];   // fp32 output
            }
        }
    }
}

extern "C" void kernel_launch(void* const* d_in, const int* in_sizes, int n_in,
                              void* d_out, int out_size, void* d_ws, size_t ws_size,
                              hipStream_t stream) {
    // Inputs fp32 (setup_inputs uses dtype=jnp.float32); output fp32.
    const float* hs = (const float*)d_in[0];
    const float* Wq = (const float*)d_in[1];
    const float* bq = (const float*)d_in[2];
    const float* Wk = (const float*)d_in[3];
    const float* bk = (const float*)d_in[4];
    const float* Wv = (const float*)d_in[5];
    const float* bv = (const float*)d_in[6];
    const float* Wo = (const float*)d_in[7];
    const float* bo = (const float*)d_in[8];
    float* out = (float*)d_out;

    // ws layout (bf16 elements): Xb[4M] Wqb[1M] Wkb[1M] Wvb[1M] Wob[1M]
    //                            qw[4M] kw[4M] vw[4M] aw[4M]  = 48 MB total
    unsigned short* Xb  = (unsigned short*)d_ws;
    unsigned short* Wqb = Xb + 4194304;
    unsigned short* Wkb = Wqb + 1048576;
    unsigned short* Wvb = Wkb + 1048576;
    unsigned short* Wob = Wvb + 1048576;
    unsigned short* qw  = Wob + 1048576;
    unsigned short* kw  = qw + 4194304;
    unsigned short* vw  = kw + 4194304;
    unsigned short* aw  = vw + 4194304;

    cvt_bf16<<<dim3(8192), 256, 0, stream>>>(hs, Wq, Wk, Wv, Wo, Xb);
    qkv_rope<<<dim3(32, 24), 256, 0, stream>>>(Xb, Wqb, bq, Wkb, bk, Wvb, bv, qw, kw, vw);
    attn_fwd<<<dim3(16, 32), 256, 0, stream>>>(qw, kw, vw, aw);
    out_proj<<<dim3(32, 8), 256, 0, stream>>>(aw, Wob, bo, out);
}